// Round 1
// baseline (688.741 us; speedup 1.0000x reference)
//
#include <hip/hip_runtime.h>
#include <math.h>

#define Bn 32
#define Sn 512
#define Hn 1024
#define Tn 8
#define Nn 16
#define Gn 4096

#define ACC4(A,W,V) A.x = fmaf(W, V.x, A.x); A.y = fmaf(W, V.y, A.y); A.z = fmaf(W, V.z, A.z); A.w = fmaf(W, V.w, A.w)
#define RSC4(A,SC,V) A.x = fmaf(A.x, SC, V.x); A.y = fmaf(A.y, SC, V.y); A.z = fmaf(A.z, SC, V.z); A.w = fmaf(A.w, SC, V.w)

__device__ __forceinline__ float wsum(float v){
#pragma unroll
  for (int off = 32; off; off >>= 1) v += __shfl_xor(v, off);
  return v;
}

__device__ __forceinline__ float dot16(float4 a0, float4 a1, float4 a2, float4 a3,
                                       float4 v0, float4 v1, float4 v2, float4 v3){
  float d = a0.x*v0.x + a0.y*v0.y + a0.z*v0.z + a0.w*v0.w;
  d += a1.x*v1.x + a1.y*v1.y + a1.z*v1.z + a1.w*v1.w;
  d += a2.x*v2.x + a2.y*v2.y + a2.z*v2.z + a2.w*v2.w;
  d += a3.x*v3.x + a3.y*v3.y + a3.z*v3.z + a3.w*v3.w;
  return d;
}

// ---------------- utility kernels ----------------

__global__ __launch_bounds__(256) void transpose1024(const float* __restrict__ in, float* __restrict__ out){
  __shared__ float tile[32][33];
  int tx = threadIdx.x & 31, ty = threadIdx.x >> 5;
  int c0 = blockIdx.x * 32, r0 = blockIdx.y * 32;
#pragma unroll
  for (int k = 0; k < 4; ++k)
    tile[ty + 8*k][tx] = in[(size_t)(r0 + ty + 8*k) * Hn + c0 + tx];
  __syncthreads();
#pragma unroll
  for (int k = 0; k < 4; ++k)
    out[(size_t)(c0 + ty + 8*k) * Hn + r0 + tx] = tile[tx][ty + 8*k];
}

__global__ __launch_bounds__(256) void copy4(const float4* __restrict__ in, float4* __restrict__ out, int n){
  int i = blockIdx.x * 256 + threadIdx.x;
  int st = gridDim.x * 256;
  for (; i < n; i += st) out[i] = in[i];
}

__global__ __launch_bounds__(256) void copy_nums(const float4* __restrict__ nums, float4* __restrict__ un){
  int n = blockIdx.x, b = blockIdx.y;
  un[((size_t)b*(Nn+Tn) + n)*256 + threadIdx.x] = nums[((size_t)b*Nn + n)*256 + threadIdx.x];
}

__global__ __launch_bounds__(256) void init_xs(const float4* __restrict__ pq, float4* __restrict__ xs){
  int b = blockIdx.x;
  xs[((size_t)b*Tn)*256 + threadIdx.x] = pq[(size_t)b*256 + threadIdx.x];
}

// write final_xs rows into updated_hidden and updated_nums
__global__ __launch_bounds__(256) void finalize_xs(const float4* __restrict__ xs, float4* __restrict__ uh, float4* __restrict__ un){
  int t = blockIdx.x, b = blockIdx.y;
  float4 v = xs[((size_t)b*Tn + t)*256 + threadIdx.x];
  uh[(((size_t)(Sn + t))*Bn + b)*256 + threadIdx.x] = v;
  un[((size_t)b*(Nn+Tn) + Nn + t)*256 + threadIdx.x] = v;
}

// ---------------- generation-loop kernels ----------------

// online-softmax attention partials. grid (8, B), block 512 (8 waves x 8 rows).
// Each wave emits an unnormalized partial (m, l, acc[1024]) -> 64 partials per b.
__global__ __launch_bounds__(512) void attend_partial(
    const float* __restrict__ hidden, const float* __restrict__ xk,
    float* __restrict__ ctxp, float* __restrict__ mlp)
{
  const int b = blockIdx.y, p = blockIdx.x;
  const int lane = threadIdx.x & 63, w = threadIdx.x >> 6;
  const int wp = p*8 + w;
  const float4* xq = (const float4*)(xk + (size_t)b*Hn) + lane*4;
  float4 q0 = xq[0], q1 = xq[1], q2 = xq[2], q3 = xq[3];
  float m = -1e30f, l = 0.f;
  float4 a0 = make_float4(0,0,0,0), a1 = a0, a2 = a0, a3 = a0;
  const int s0 = p*64 + w*8;
#pragma unroll 2
  for (int r = 0; r < 8; ++r){
    const float4* row = (const float4*)(hidden + ((size_t)(s0+r)*Bn + b)*Hn) + lane*4;
    float4 v0 = row[0], v1 = row[1], v2 = row[2], v3 = row[3];
    float d = wsum(dot16(q0,q1,q2,q3, v0,v1,v2,v3));
    if (d <= m){                       // wave-uniform branch (d is wave-reduced)
      float wt = __expf(d - m);
      l += wt;
      ACC4(a0, wt, v0); ACC4(a1, wt, v1); ACC4(a2, wt, v2); ACC4(a3, wt, v3);
    } else {
      float sc = __expf(m - d);
      m = d;
      l = fmaf(l, sc, 1.f);
      RSC4(a0, sc, v0); RSC4(a1, sc, v1); RSC4(a2, sc, v2); RSC4(a3, sc, v3);
    }
  }
  float4* cp = (float4*)(ctxp + ((size_t)b*64 + wp)*Hn) + lane*4;
  cp[0] = a0; cp[1] = a1; cp[2] = a2; cp[3] = a3;
  if (lane == 0){
    mlp[((size_t)b*64 + wp)*2]   = m;
    mlp[((size_t)b*64 + wp)*2+1] = l;
  }
}

// merge 64 partials per b -> normalized ctx[b][1024]. grid (B), block 256.
__global__ __launch_bounds__(256) void combine_ctx(
    const float* __restrict__ ctxp, const float* __restrict__ mlp, float* __restrict__ ctx)
{
  int b = blockIdx.x, tid = threadIdx.x;
  __shared__ float sm[64], sl[64], sw[64];
  if (tid < 64){ sm[tid] = mlp[((size_t)b*64+tid)*2]; sl[tid] = mlp[((size_t)b*64+tid)*2+1]; }
  __syncthreads();
  float M = sm[0];
#pragma unroll
  for (int i = 1; i < 64; ++i) M = fmaxf(M, sm[i]);
  if (tid < 64) sw[tid] = __expf(sm[tid] - M);
  __syncthreads();
  float L = 0.f;
#pragma unroll
  for (int i = 0; i < 64; ++i) L = fmaf(sl[i], sw[i], L);
  float inv = 1.f / L;
  float4 acc = make_float4(0,0,0,0);
  for (int i = 0; i < 64; ++i){
    float4 v = *(const float4*)(ctxp + ((size_t)b*64 + i)*Hn + tid*4);
    float wv = sw[i];
    ACC4(acc, wv, v);
  }
  acc.x *= inv; acc.y *= inv; acc.z *= inv; acc.w *= inv;
  *(float4*)(ctx + (size_t)b*Hn + tid*4) = acc;
}

// generic row-matvec: out[orow(r)*nj + j] = bias1[j]+bias2[j] + sum_i in[r*in_stride+i]*W[j*1024+i]
// grid (nj/4, row_chunks), block 256 (4 waves, wave = one j).
__global__ __launch_bounds__(256) void matvec(
    const float* __restrict__ in, int in_stride,
    const float* __restrict__ W, const float* __restrict__ b1, const float* __restrict__ b2,
    float* __restrict__ out, int nj, int nrows, int rpg, int opg)
{
  int lane = threadIdx.x & 63, w = threadIdx.x >> 6;
  int j = blockIdx.x*4 + w;
  const float4* Wj = (const float4*)(W + (size_t)j*Hn) + lane*4;
  float4 q0 = Wj[0], q1 = Wj[1], q2 = Wj[2], q3 = Wj[3];
  float bias = (b1 ? b1[j] : 0.f) + (b2 ? b2[j] : 0.f);
  int r0 = blockIdx.y*32;
  int r1 = min(r0 + 32, nrows);
  for (int r = r0; r < r1; ++r){
    const float4* x = (const float4*)(in + (size_t)r*in_stride) + lane*4;
    float4 v0 = x[0], v1 = x[1], v2 = x[2], v3 = x[3];
    float d = wsum(dot16(q0,q1,q2,q3, v0,v1,v2,v3));
    if (lane == 0){
      int orow = (r / rpg) * opg + (r % rpg);
      out[(size_t)orow*nj + j] = d + bias;
    }
  }
}

// ---------------- stage-2 kernels ----------------

// scores2[b][t][s] = xk2[b][t] . hidden[s][b]. grid (8, B), block 512.
// wave w: t-pair (w&3), row-half (w>>2): 2 queries in regs, 32 rows each.
__global__ __launch_bounds__(512) void scores2_kernel(
    const float* __restrict__ hidden, const float* __restrict__ xk2, float* __restrict__ sc)
{
  int b = blockIdx.y, p = blockIdx.x;
  int lane = threadIdx.x & 63, w = threadIdx.x >> 6;
  int t0 = (w & 3) * 2, rh = w >> 2;
  const float4* qa = (const float4*)(xk2 + ((size_t)b*Tn + t0  )*Hn) + lane*4;
  const float4* qb = (const float4*)(xk2 + ((size_t)b*Tn + t0+1)*Hn) + lane*4;
  float4 a0=qa[0], a1=qa[1], a2=qa[2], a3=qa[3];
  float4 c0=qb[0], c1=qb[1], c2=qb[2], c3=qb[3];
  for (int r = 0; r < 32; ++r){
    int s = p*64 + rh*32 + r;
    const float4* row = (const float4*)(hidden + ((size_t)s*Bn + b)*Hn) + lane*4;
    float4 v0=row[0], v1=row[1], v2=row[2], v3=row[3];
    float d0 = wsum(dot16(a0,a1,a2,a3, v0,v1,v2,v3));
    float d1 = wsum(dot16(c0,c1,c2,c3, v0,v1,v2,v3));
    if (lane == 0){
      sc[((size_t)b*Tn + t0  )*Sn + s] = d0;
      sc[((size_t)b*Tn + t0+1)*Sn + s] = d1;
    }
  }
}

// in-place softmax over 512 elems. grid (B*T), block 512.
__global__ __launch_bounds__(512) void softmax512(float* __restrict__ sc){
  int row = blockIdx.x, tid = threadIdx.x, lane = tid & 63, w = tid >> 6;
  float v = sc[(size_t)row*Sn + tid];
  float mx = v;
#pragma unroll
  for (int off = 32; off; off >>= 1) mx = fmaxf(mx, __shfl_xor(mx, off));
  __shared__ float sm[8], ss[8];
  if (lane == 0) sm[w] = mx;
  __syncthreads();
  mx = sm[0];
#pragma unroll
  for (int i = 1; i < 8; ++i) mx = fmaxf(mx, sm[i]);
  float e = __expf(v - mx);
  float s = e;
#pragma unroll
  for (int off = 32; off; off >>= 1) s += __shfl_xor(s, off);
  if (lane == 0) ss[w] = s;
  __syncthreads();
  float tot = 0.f;
#pragma unroll
  for (int i = 0; i < 8; ++i) tot += ss[i];
  sc[(size_t)row*Sn + tid] = e / tot;
}

// ctx2[b][t][h] = sum_s attn[b][t][s] * hidden[s][b][h]. grid (8, B), block 512.
__global__ __launch_bounds__(512) void ctx2_kernel(
    const float* __restrict__ hidden, const float* __restrict__ attn, float* __restrict__ ctx2)
{
  int b = blockIdx.y, hc = blockIdx.x;
  int hloc = threadIdx.x & 127, tg = threadIdx.x >> 7;   // 4 t-groups x 2 t each
  int h = hc*128 + hloc;
  __shared__ float al[Tn*Sn];
  for (int i = threadIdx.x; i < Tn*Sn; i += 512) al[i] = attn[(size_t)b*Tn*Sn + i];
  __syncthreads();
  int t0 = tg*2;
  float acc0 = 0.f, acc1 = 0.f;
#pragma unroll 4
  for (int s = 0; s < Sn; ++s){
    float v = hidden[((size_t)s*Bn + b)*Hn + h];
    acc0 = fmaf(al[t0*Sn + s],     v, acc0);
    acc1 = fmaf(al[(t0+1)*Sn + s], v, acc1);
  }
  ctx2[((size_t)b*Tn + t0  )*Hn + h] = acc0;
  ctx2[((size_t)b*Tn + t0+1)*Hn + h] = acc1;
}

// ---------------- LSTM (only step 1 is observable; h0=c0=0 so W_hh drops) ----------------
__global__ __launch_bounds__(256) void lstm_final(const float* __restrict__ gates, float* __restrict__ fq){
  int b = blockIdx.x;
#pragma unroll
  for (int k = 0; k < 4; ++k){
    int h = threadIdx.x + k*256;
    float gi = gates[(size_t)b*Gn + h];
    float gg = gates[(size_t)b*Gn + 2048 + h];
    float go = gates[(size_t)b*Gn + 3072 + h];
    float si = 1.f / (1.f + __expf(-gi));
    float so = 1.f / (1.f + __expf(-go));
    float c  = si * tanhf(gg);
    fq[((size_t)b*(Tn+1) + Tn)*Hn + h] = so * tanhf(c);
  }
}

// ---------------- host ----------------

extern "C" void kernel_launch(void* const* d_in, const int* in_sizes, int n_in,
                              void* d_out, int out_size, void* d_ws, size_t ws_size,
                              hipStream_t stream) {
  const float* hidden = (const float*)d_in[0];   // (S,B,H)
  const float* nums   = (const float*)d_in[1];   // (B,N,H)
  const float* pq     = (const float*)d_in[2];   // (B,H)
  const float* Wk     = (const float*)d_in[3];
  const float* Wv     = (const float*)d_in[5];
  const float* bv     = (const float*)d_in[6];
  const float* Wk2    = (const float*)d_in[7];
  const float* Wv2    = (const float*)d_in[9];
  const float* bv2    = (const float*)d_in[10];
  const float* W_ih   = (const float*)d_in[11];
  const float* b_ih   = (const float*)d_in[13];
  const float* b_hh   = (const float*)d_in[14];

  float* out = (float*)d_out;
  float* fq  = out;                                   // (B, T+1, H)
  float* uh  = out + (size_t)Bn*(Tn+1)*Hn;            // (S+T, B, H)
  float* un  = uh + (size_t)(Sn+Tn)*Bn*Hn;            // (B, N+T, H)

  float* ws    = (float*)d_ws;
  float* xs    = ws;                 // B*T*H          = 262144
  float* xk    = ws + 262144;        // B*H            = 32768
  float* ctxp  = ws + 294912;        // B*64*H         = 2097152
  float* mlp   = ws + 2392064;       // B*64*2         = 4096
  float* ctx   = ws + 2396160;       // B*H            = 32768
  float* xk2   = ws + 2428928;       // B*T*H          = 262144
  float* sc2   = ws + 2691072;       // B*T*S          = 131072
  float* ctx2v = ws + 2822144;       // B*T*H          = 262144
  float* gates = ws + 3084288;       // B*4H           = 131072
  float* WkT   = ws + 3215360;       // H*H            = 1048576
  float* Wk2T  = ws + 4263936;       // H*H            = 1048576

  // one-time prep
  transpose1024<<<dim3(32,32), 256, 0, stream>>>(Wk,  WkT);
  transpose1024<<<dim3(32,32), 256, 0, stream>>>(Wk2, Wk2T);
  copy4<<<2048, 256, 0, stream>>>((const float4*)hidden, (float4*)uh, (Sn*Bn*Hn)/4);
  copy_nums<<<dim3(Nn, Bn), 256, 0, stream>>>((const float4*)nums, (float4*)un);
  init_xs<<<Bn, 256, 0, stream>>>((const float4*)pq, (float4*)xs);

  // xk0 = problem_q @ Wk
  matvec<<<dim3(Hn/4, 1), 256, 0, stream>>>(pq, Hn, WkT, nullptr, nullptr, xk, Hn, Bn, 1, 1);

  // generation loop: x_t = Wv * ctx_t + bv ; xk_t = x_t @ Wk
  for (int t = 1; t < Tn; ++t){
    attend_partial<<<dim3(8, Bn), 512, 0, stream>>>(hidden, xk, ctxp, mlp);
    combine_ctx<<<Bn, 256, 0, stream>>>(ctxp, mlp, ctx);
    matvec<<<dim3(Hn/4, 1), 256, 0, stream>>>(ctx, Hn, Wv, bv, nullptr, xs + (size_t)t*Hn, Hn, Bn, 1, Tn);
    if (t < Tn-1)
      matvec<<<dim3(Hn/4, 1), 256, 0, stream>>>(xs + (size_t)t*Hn, Tn*Hn, WkT, nullptr, nullptr, xk, Hn, Bn, 1, 1);
  }

  // stage 2: attention of final_xs over hidden with Wk2/Wv2
  matvec<<<dim3(Hn/4, 8), 256, 0, stream>>>(xs, Hn, Wk2T, nullptr, nullptr, xk2, Hn, Bn*Tn, 1, 1);
  scores2_kernel<<<dim3(8, Bn), 512, 0, stream>>>(hidden, xk2, sc2);
  softmax512<<<Bn*Tn, 512, 0, stream>>>(sc2);
  ctx2_kernel<<<dim3(8, Bn), 512, 0, stream>>>(hidden, sc2, ctx2v);
  // qs -> final_qs rows (b*9 + t)
  matvec<<<dim3(Hn/4, 8), 256, 0, stream>>>(ctx2v, Hn, Wv2, bv2, nullptr, fq, Hn, Bn*Tn, Tn, Tn+1);

  // LSTM step 1 only: gates = qs[:,0,:] @ W_ih^T + b_ih + b_hh
  matvec<<<dim3(Gn/4, 1), 256, 0, stream>>>(fq, (Tn+1)*Hn, W_ih, b_ih, b_hh, gates, Gn, Bn, 1, 1);
  lstm_final<<<Bn, 256, 0, stream>>>(gates, fq);

  // write final_xs into updated_hidden / updated_nums
  finalize_xs<<<dim3(Tn, Bn), 256, 0, stream>>>((const float4*)xs, (float4*)uh, (float4*)un);
}

// Round 2
// 454.247 us; speedup vs baseline: 1.5162x; 1.5162x over previous
//
#include <hip/hip_runtime.h>
#include <math.h>

#define Bn 32
#define Sn 512
#define Hn 1024
#define Tn 8
#define Nn 16
#define Gn 4096

#define ACC4(A,W,V) A.x = fmaf(W, V.x, A.x); A.y = fmaf(W, V.y, A.y); A.z = fmaf(W, V.z, A.z); A.w = fmaf(W, V.w, A.w)
#define RSC4(A,SC,V) A.x = fmaf(A.x, SC, V.x); A.y = fmaf(A.y, SC, V.y); A.z = fmaf(A.z, SC, V.z); A.w = fmaf(A.w, SC, V.w)

__device__ __forceinline__ float wsum(float v){
#pragma unroll
  for (int off = 32; off; off >>= 1) v += __shfl_xor(v, off);
  return v;
}

__device__ __forceinline__ float dot16(float4 a0, float4 a1, float4 a2, float4 a3,
                                       float4 v0, float4 v1, float4 v2, float4 v3){
  float d = a0.x*v0.x + a0.y*v0.y + a0.z*v0.z + a0.w*v0.w;
  d += a1.x*v1.x + a1.y*v1.y + a1.z*v1.z + a1.w*v1.w;
  d += a2.x*v2.x + a2.y*v2.y + a2.z*v2.z + a2.w*v2.w;
  d += a3.x*v3.x + a3.y*v3.y + a3.z*v3.z + a3.w*v3.w;
  return d;
}

// ---------------- utility kernels ----------------

__global__ __launch_bounds__(256) void transpose1024(const float* __restrict__ in, float* __restrict__ out){
  __shared__ float tile[32][33];
  int tx = threadIdx.x & 31, ty = threadIdx.x >> 5;
  int c0 = blockIdx.x * 32, r0 = blockIdx.y * 32;
#pragma unroll
  for (int k = 0; k < 4; ++k)
    tile[ty + 8*k][tx] = in[(size_t)(r0 + ty + 8*k) * Hn + c0 + tx];
  __syncthreads();
#pragma unroll
  for (int k = 0; k < 4; ++k)
    out[(size_t)(c0 + ty + 8*k) * Hn + r0 + tx] = tile[tx][ty + 8*k];
}

__global__ __launch_bounds__(256) void copy_nums(const float4* __restrict__ nums, float4* __restrict__ un){
  int n = blockIdx.x, b = blockIdx.y;
  un[((size_t)b*(Nn+Tn) + n)*256 + threadIdx.x] = nums[((size_t)b*Nn + n)*256 + threadIdx.x];
}

__global__ __launch_bounds__(256) void init_xs(const float4* __restrict__ pq, float4* __restrict__ xs){
  int b = blockIdx.x;
  xs[((size_t)b*Tn)*256 + threadIdx.x] = pq[(size_t)b*256 + threadIdx.x];
}

__global__ __launch_bounds__(256) void finalize_xs(const float4* __restrict__ xs, float4* __restrict__ uh, float4* __restrict__ un){
  int t = blockIdx.x, b = blockIdx.y;
  float4 v = xs[((size_t)b*Tn + t)*256 + threadIdx.x];
  uh[(((size_t)(Sn + t))*Bn + b)*256 + threadIdx.x] = v;
  un[((size_t)b*(Nn+Tn) + Nn + t)*256 + threadIdx.x] = v;
}

// ---------------- generation-loop kernels ----------------

// online-softmax attention partials. grid (8, B), block 512 (8 waves x 8 rows).
// WRITE_UH: also copy the hidden rows into updated_hidden (folds the 64MB copy).
template<int WRITE_UH>
__global__ __launch_bounds__(512) void attend_partial(
    const float* __restrict__ hidden, const float* __restrict__ xk,
    float* __restrict__ ctxp, float* __restrict__ mlp, float* __restrict__ uh)
{
  const int b = blockIdx.y, p = blockIdx.x;
  const int lane = threadIdx.x & 63, w = threadIdx.x >> 6;
  const int wp = p*8 + w;
  const float4* xq = (const float4*)(xk + (size_t)b*Hn) + lane*4;
  float4 q0 = xq[0], q1 = xq[1], q2 = xq[2], q3 = xq[3];
  float m = -1e30f, l = 0.f;
  float4 a0 = make_float4(0,0,0,0), a1 = a0, a2 = a0, a3 = a0;
  const int s0 = p*64 + w*8;
#pragma unroll 2
  for (int r = 0; r < 8; ++r){
    const size_t rowoff = ((size_t)(s0+r)*Bn + b)*Hn;
    const float4* row = (const float4*)(hidden + rowoff) + lane*4;
    float4 v0 = row[0], v1 = row[1], v2 = row[2], v3 = row[3];
    if (WRITE_UH){
      float4* ur = (float4*)(uh + rowoff) + lane*4;
      ur[0] = v0; ur[1] = v1; ur[2] = v2; ur[3] = v3;
    }
    float d = wsum(dot16(q0,q1,q2,q3, v0,v1,v2,v3));
    if (d <= m){                       // wave-uniform branch (d is wave-reduced)
      float wt = __expf(d - m);
      l += wt;
      ACC4(a0, wt, v0); ACC4(a1, wt, v1); ACC4(a2, wt, v2); ACC4(a3, wt, v3);
    } else {
      float sc = __expf(m - d);
      m = d;
      l = fmaf(l, sc, 1.f);
      RSC4(a0, sc, v0); RSC4(a1, sc, v1); RSC4(a2, sc, v2); RSC4(a3, sc, v3);
    }
  }
  float4* cp = (float4*)(ctxp + ((size_t)b*64 + wp)*Hn) + lane*4;
  cp[0] = a0; cp[1] = a1; cp[2] = a2; cp[3] = a3;
  if (lane == 0){
    mlp[((size_t)b*64 + wp)*2]   = m;
    mlp[((size_t)b*64 + wp)*2+1] = l;
  }
}

// merge 64 partials per b -> normalized ctx[b][1024]. grid (4 hchunk, B), block 64.
__global__ __launch_bounds__(64) void combine_ctx(
    const float* __restrict__ ctxp, const float* __restrict__ mlp, float* __restrict__ ctx)
{
  int b = blockIdx.y, hc = blockIdx.x, lane = threadIdx.x;
  __shared__ float wl[64];
  float m = mlp[((size_t)b*64 + lane)*2];
  float l = mlp[((size_t)b*64 + lane)*2 + 1];
  float M = m;
#pragma unroll
  for (int off = 32; off; off >>= 1) M = fmaxf(M, __shfl_xor(M, off));
  float w = __expf(m - M);
  float L = wsum(l * w);
  wl[lane] = w;
  __syncthreads();
  float4 acc = make_float4(0,0,0,0);
  const float* cp = ctxp + (size_t)b*64*Hn + hc*256 + lane*4;
  for (int i = 0; i < 64; ++i){
    float4 v = *(const float4*)(cp + (size_t)i*Hn);
    float wi = wl[i];
    ACC4(acc, wi, v);
  }
  float inv = 1.f / L;
  acc.x *= inv; acc.y *= inv; acc.z *= inv; acc.w *= inv;
  *(float4*)(ctx + (size_t)b*Hn + hc*256 + lane*4) = acc;
}

// ---------------- split-K register-tiled matvec ----------------
// out[r][j] = bias[j] + sum_k X[r][k] * M[j][k]   (M row-major [nj][1024])
// mv1: grid (nj/128, KB, nrows/32), block 256. Each block: 128j x 32r x (ktiles*64)k.
// Thread tile 4r x 4j, fed by two ds_read_b128 per k.
__global__ __launch_bounds__(256) void mv1(
    const float* __restrict__ X, int xstride,
    const float* __restrict__ M, float* __restrict__ part,
    int nj, int ktiles)
{
  __shared__ float wt[64*128];   // wt[k][j]
  __shared__ float xl[64*32];    // xl[k][r]
  const int t  = threadIdx.x;
  const int j0 = blockIdx.x * 128;
  const int kb = blockIdx.y;
  const int r0 = blockIdx.z * 32;
  const int R  = gridDim.z * 32;
  const int tj = t & 31, tr = t >> 5;
  float acc[4][4] = {{0.f,0.f,0.f,0.f},{0.f,0.f,0.f,0.f},{0.f,0.f,0.f,0.f},{0.f,0.f,0.f,0.f}};

  for (int kt = 0; kt < ktiles; ++kt){
    const int k0 = (kb*ktiles + kt)*64;
    __syncthreads();
    {
      // stage W tile transposed: wt[k][j] = M[j0+j][k0+k]
      int j = t >> 1;
      int kqb = (t & 1) * 8;
      const float* Mrow = M + (size_t)(j0 + j)*1024 + k0;
#pragma unroll
      for (int c = 0; c < 8; ++c){
        float4 v = *(const float4*)(Mrow + (kqb + c)*4);
        int kk = (kqb + c)*4;
        wt[(kk+0)*128 + j] = v.x;
        wt[(kk+1)*128 + j] = v.y;
        wt[(kk+2)*128 + j] = v.z;
        wt[(kk+3)*128 + j] = v.w;
      }
      // stage X tile transposed: xl[k][r] = X[r0+r][k0+k]
      int r = t >> 3;
      int kq0 = t & 7;
#pragma unroll
      for (int c = 0; c < 2; ++c){
        int kk = (kq0 + c*8)*4;
        float4 v = *(const float4*)(X + (size_t)(r0 + r)*xstride + k0 + kk);
        xl[(kk+0)*32 + r] = v.x;
        xl[(kk+1)*32 + r] = v.y;
        xl[(kk+2)*32 + r] = v.z;
        xl[(kk+3)*32 + r] = v.w;
      }
    }
    __syncthreads();
#pragma unroll 4
    for (int k = 0; k < 64; ++k){
      float4 w4 = *(const float4*)(wt + k*128 + tj*4);
      float4 x4 = *(const float4*)(xl + k*32  + tr*4);
      acc[0][0] = fmaf(x4.x, w4.x, acc[0][0]);
      acc[0][1] = fmaf(x4.x, w4.y, acc[0][1]);
      acc[0][2] = fmaf(x4.x, w4.z, acc[0][2]);
      acc[0][3] = fmaf(x4.x, w4.w, acc[0][3]);
      acc[1][0] = fmaf(x4.y, w4.x, acc[1][0]);
      acc[1][1] = fmaf(x4.y, w4.y, acc[1][1]);
      acc[1][2] = fmaf(x4.y, w4.z, acc[1][2]);
      acc[1][3] = fmaf(x4.y, w4.w, acc[1][3]);
      acc[2][0] = fmaf(x4.z, w4.x, acc[2][0]);
      acc[2][1] = fmaf(x4.z, w4.y, acc[2][1]);
      acc[2][2] = fmaf(x4.z, w4.z, acc[2][2]);
      acc[2][3] = fmaf(x4.z, w4.w, acc[2][3]);
      acc[3][0] = fmaf(x4.w, w4.x, acc[3][0]);
      acc[3][1] = fmaf(x4.w, w4.y, acc[3][1]);
      acc[3][2] = fmaf(x4.w, w4.z, acc[3][2]);
      acc[3][3] = fmaf(x4.w, w4.w, acc[3][3]);
    }
  }
  const size_t base = ((size_t)kb*R + r0 + tr*4)*nj + j0 + tj*4;
#pragma unroll
  for (int i = 0; i < 4; ++i)
    *(float4*)(part + base + (size_t)i*nj) = make_float4(acc[i][0], acc[i][1], acc[i][2], acc[i][3]);
}

// mv2: reduce KB partials + bias + row remap. grid (R*nj/256), block 256.
__global__ __launch_bounds__(256) void mv2(
    const float* __restrict__ part, int R, int njshift, int KB,
    const float* __restrict__ b1, const float* __restrict__ b2,
    float* __restrict__ out, int rpgshift, int opg)
{
  int idx = blockIdx.x*256 + threadIdx.x;
  int nj = 1 << njshift;
  int r = idx >> njshift, j = idx & (nj - 1);
  float s = 0.f;
  if (b1) s += b1[j];
  if (b2) s += b2[j];
  size_t stride = (size_t)R << njshift;
  for (int kb = 0; kb < KB; ++kb) s += part[(size_t)kb*stride + idx];
  int orow = ((r >> rpgshift) * opg) + (r & ((1 << rpgshift) - 1));
  out[((size_t)orow << njshift) + j] = s;
}

// ---------------- stage-2 kernels ----------------

__global__ __launch_bounds__(512) void scores2_kernel(
    const float* __restrict__ hidden, const float* __restrict__ xk2, float* __restrict__ sc)
{
  int b = blockIdx.y, p = blockIdx.x;
  int lane = threadIdx.x & 63, w = threadIdx.x >> 6;
  int t0 = (w & 3) * 2, rh = w >> 2;
  const float4* qa = (const float4*)(xk2 + ((size_t)b*Tn + t0  )*Hn) + lane*4;
  const float4* qb = (const float4*)(xk2 + ((size_t)b*Tn + t0+1)*Hn) + lane*4;
  float4 a0=qa[0], a1=qa[1], a2=qa[2], a3=qa[3];
  float4 c0=qb[0], c1=qb[1], c2=qb[2], c3=qb[3];
  for (int r = 0; r < 32; ++r){
    int s = p*64 + rh*32 + r;
    const float4* row = (const float4*)(hidden + ((size_t)s*Bn + b)*Hn) + lane*4;
    float4 v0=row[0], v1=row[1], v2=row[2], v3=row[3];
    float d0 = wsum(dot16(a0,a1,a2,a3, v0,v1,v2,v3));
    float d1 = wsum(dot16(c0,c1,c2,c3, v0,v1,v2,v3));
    if (lane == 0){
      sc[((size_t)b*Tn + t0  )*Sn + s] = d0;
      sc[((size_t)b*Tn + t0+1)*Sn + s] = d1;
    }
  }
}

__global__ __launch_bounds__(512) void softmax512(float* __restrict__ sc){
  int row = blockIdx.x, tid = threadIdx.x, lane = tid & 63, w = tid >> 6;
  float v = sc[(size_t)row*Sn + tid];
  float mx = v;
#pragma unroll
  for (int off = 32; off; off >>= 1) mx = fmaxf(mx, __shfl_xor(mx, off));
  __shared__ float sm[8], ss[8];
  if (lane == 0) sm[w] = mx;
  __syncthreads();
  mx = sm[0];
#pragma unroll
  for (int i = 1; i < 8; ++i) mx = fmaxf(mx, sm[i]);
  float e = __expf(v - mx);
  float s = e;
#pragma unroll
  for (int off = 32; off; off >>= 1) s += __shfl_xor(s, off);
  if (lane == 0) ss[w] = s;
  __syncthreads();
  float tot = 0.f;
#pragma unroll
  for (int i = 0; i < 8; ++i) tot += ss[i];
  sc[(size_t)row*Sn + tid] = e / tot;
}

__global__ __launch_bounds__(512) void ctx2_kernel(
    const float* __restrict__ hidden, const float* __restrict__ attn, float* __restrict__ ctx2)
{
  int b = blockIdx.y, hc = blockIdx.x;
  int hloc = threadIdx.x & 127, tg = threadIdx.x >> 7;
  int h = hc*128 + hloc;
  __shared__ float al[Tn*Sn];
  for (int i = threadIdx.x; i < Tn*Sn; i += 512) al[i] = attn[(size_t)b*Tn*Sn + i];
  __syncthreads();
  int t0 = tg*2;
  float acc0 = 0.f, acc1 = 0.f;
#pragma unroll 4
  for (int s = 0; s < Sn; ++s){
    float v = hidden[((size_t)s*Bn + b)*Hn + h];
    acc0 = fmaf(al[t0*Sn + s],     v, acc0);
    acc1 = fmaf(al[(t0+1)*Sn + s], v, acc1);
  }
  ctx2[((size_t)b*Tn + t0  )*Hn + h] = acc0;
  ctx2[((size_t)b*Tn + t0+1)*Hn + h] = acc1;
}

// ---------------- LSTM (only step 1 observable; h0=c0=0 so W_hh drops) ----------------
__global__ __launch_bounds__(256) void lstm_final(const float* __restrict__ gates, float* __restrict__ fq){
  int b = blockIdx.x;
#pragma unroll
  for (int k = 0; k < 4; ++k){
    int h = threadIdx.x + k*256;
    float gi = gates[(size_t)b*Gn + h];
    float gg = gates[(size_t)b*Gn + 2048 + h];
    float go = gates[(size_t)b*Gn + 3072 + h];
    float si = 1.f / (1.f + __expf(-gi));
    float so = 1.f / (1.f + __expf(-go));
    float c  = si * tanhf(gg);
    fq[((size_t)b*(Tn+1) + Tn)*Hn + h] = so * tanhf(c);
  }
}

// ---------------- host ----------------

extern "C" void kernel_launch(void* const* d_in, const int* in_sizes, int n_in,
                              void* d_out, int out_size, void* d_ws, size_t ws_size,
                              hipStream_t stream) {
  const float* hidden = (const float*)d_in[0];   // (S,B,H)
  const float* nums   = (const float*)d_in[1];   // (B,N,H)
  const float* pq     = (const float*)d_in[2];   // (B,H)
  const float* Wk     = (const float*)d_in[3];
  const float* Wv     = (const float*)d_in[5];
  const float* bv     = (const float*)d_in[6];
  const float* Wk2    = (const float*)d_in[7];
  const float* Wv2    = (const float*)d_in[9];
  const float* bv2    = (const float*)d_in[10];
  const float* W_ih   = (const float*)d_in[11];
  const float* b_ih   = (const float*)d_in[13];
  const float* b_hh   = (const float*)d_in[14];

  float* out = (float*)d_out;
  float* fq  = out;                                   // (B, T+1, H)
  float* uh  = out + (size_t)Bn*(Tn+1)*Hn;            // (S+T, B, H)
  float* un  = uh + (size_t)(Sn+Tn)*Bn*Hn;            // (B, N+T, H)

  float* ws    = (float*)d_ws;
  float* xs    = ws;                 // B*T*H          = 262144
  float* xk    = ws + 262144;        // B*H            = 32768
  float* ctxp  = ws + 294912;        // B*64*H         = 2097152 (also mv partials)
  float* mlp   = ws + 2392064;       // B*64*2         = 4096
  float* ctx   = ws + 2396160;       // B*H            = 32768
  float* xk2   = ws + 2428928;       // B*T*H          = 262144
  float* sc2   = ws + 2691072;       // B*T*S          = 131072
  float* ctx2v = ws + 2822144;       // B*T*H          = 262144
  float* gates = ws + 3084288;       // B*4H           = 131072
  float* WkT   = ws + 3215360;       // H*H            = 1048576
  float* Wk2T  = ws + 4263936;       // H*H            = 1048576
  float* part  = ctxp;               // split-K partials overlay ctxp (disjoint lifetime)

  // one-time prep
  transpose1024<<<dim3(32,32), 256, 0, stream>>>(Wk,  WkT);
  transpose1024<<<dim3(32,32), 256, 0, stream>>>(Wk2, Wk2T);
  copy_nums<<<dim3(Nn, Bn), 256, 0, stream>>>((const float4*)nums, (float4*)un);
  init_xs<<<Bn, 256, 0, stream>>>((const float4*)pq, (float4*)xs);

  // xk0 = Wk^T problem_q
  mv1<<<dim3(8,16,1), 256, 0, stream>>>(pq, Hn, WkT, part, Hn, 1);
  mv2<<<128, 256, 0, stream>>>(part, 32, 10, 16, nullptr, nullptr, xk, 0, 1);

  // generation loop: ctx_t = attend(xk); x_t = Wv ctx + bv; xk = Wk^T x_t
  for (int t = 1; t < Tn; ++t){
    if (t == 1) attend_partial<1><<<dim3(8, Bn), 512, 0, stream>>>(hidden, xk, ctxp, mlp, uh);
    else        attend_partial<0><<<dim3(8, Bn), 512, 0, stream>>>(hidden, xk, ctxp, mlp, uh);
    combine_ctx<<<dim3(4, Bn), 64, 0, stream>>>(ctxp, mlp, ctx);
    mv1<<<dim3(8,16,1), 256, 0, stream>>>(ctx, Hn, Wv, part, Hn, 1);
    mv2<<<128, 256, 0, stream>>>(part, 32, 10, 16, bv, nullptr, xs + (size_t)t*Hn, 0, Tn);
    if (t < Tn-1){
      mv1<<<dim3(8,16,1), 256, 0, stream>>>(xs + (size_t)t*Hn, Tn*Hn, WkT, part, Hn, 1);
      mv2<<<128, 256, 0, stream>>>(part, 32, 10, 16, nullptr, nullptr, xk, 0, 1);
    }
  }

  // stage 2: xk2 = Wk2^T final_xs (256 rows)
  mv1<<<dim3(8,4,8), 256, 0, stream>>>(xs, Hn, Wk2T, part, Hn, 4);
  mv2<<<1024, 256, 0, stream>>>(part, 256, 10, 4, nullptr, nullptr, xk2, 0, 1);
  scores2_kernel<<<dim3(8, Bn), 512, 0, stream>>>(hidden, xk2, sc2);
  softmax512<<<Bn*Tn, 512, 0, stream>>>(sc2);
  ctx2_kernel<<<dim3(8, Bn), 512, 0, stream>>>(hidden, sc2, ctx2v);
  // qs = Wv2 ctx2 + bv2 -> fq rows (b*9 + t)
  mv1<<<dim3(8,4,8), 256, 0, stream>>>(ctx2v, Hn, Wv2, part, Hn, 4);
  mv2<<<1024, 256, 0, stream>>>(part, 256, 10, 4, bv2, nullptr, fq, 3, Tn+1);

  // LSTM step 1: gates = W_ih qs[:,0,:] + b_ih + b_hh
  mv1<<<dim3(32,16,1), 256, 0, stream>>>(fq, (Tn+1)*Hn, W_ih, part, Gn, 1);
  mv2<<<512, 256, 0, stream>>>(part, 32, 12, 16, b_ih, b_hh, gates, 0, 1);
  lstm_final<<<Bn, 256, 0, stream>>>(gates, fq);

  finalize_xs<<<dim3(Tn, Bn), 256, 0, stream>>>((const float4*)xs, (float4*)uh, (float4*)un);
}